// Round 4
// baseline (1208.026 us; speedup 1.0000x reference)
//
#include <hip/hip_runtime.h>
#include <math.h>

#define BB  8
#define KTT 2
#define THH 12
#define NN  2048
#define DII 32
#define DHD 64
#define DEE 24
#define CC  96
#define BT  16      // BB*KTT
#define RT  64      // row tile
#define MT  64      // m tile

typedef __attribute__((ext_vector_type(8))) short short8;   // 8 bf16 = 4 VGPRs
typedef __attribute__((ext_vector_type(4))) float f32x4;

#define MFMA16(a, b, c) __builtin_amdgcn_mfma_f32_16x16x32_bf16(a, b, c, 0, 0, 0)

__device__ __forceinline__ unsigned short f2bf(float f) {
  unsigned u = __builtin_bit_cast(unsigned, f);
  u += 0x7FFFu + ((u >> 16) & 1u);
  return (unsigned short)(u >> 16);
}
__device__ __forceinline__ float bf2f(unsigned short h) {
  return __builtin_bit_cast(float, ((unsigned)h) << 16);
}
__device__ __forceinline__ unsigned pack2(float a, float b) {
  return (unsigned)f2bf(a) | ((unsigned)f2bf(b) << 16);
}

// ---- LN(node_emb + time_emb)*g + b (eps 1e-12) -> bf16 hi/lo, two gates ----
__global__ void k_emb2(const float* __restrict__ node_emb,
                       const float* __restrict__ time_emb,
                       const float* __restrict__ gZ, const float* __restrict__ bZ,
                       const float* __restrict__ gR, const float* __restrict__ bR,
                       unsigned* __restrict__ ehZ, unsigned* __restrict__ elZ,
                       unsigned* __restrict__ ehR, unsigned* __restrict__ elR) {
  int idx = blockIdx.x * 256 + threadIdx.x;   // bt*NN + n
  int n  = idx & (NN - 1);
  int bt = idx >> 11;
  float v[DEE];
  float mean = 0.f;
#pragma unroll
  for (int d = 0; d < DEE; ++d) {
    v[d] = node_emb[n * DEE + d] + time_emb[bt * DEE + d];
    mean += v[d];
  }
  mean *= (1.f / DEE);
  float var = 0.f;
#pragma unroll
  for (int d = 0; d < DEE; ++d) { float u = v[d] - mean; var += u * u; }
  var *= (1.f / DEE);
  float inv = 1.f / sqrtf(var + 1e-12f);
#pragma unroll
  for (int gate = 0; gate < 2; ++gate) {
    const float* ga = gate ? gR : gZ;
    const float* ba = gate ? bR : bZ;
    unsigned* dh = (gate ? ehR : ehZ) + (size_t)idx * 16;
    unsigned* dl = (gate ? elR : elZ) + (size_t)idx * 16;
    unsigned hi[16], lo[16];
#pragma unroll
    for (int q = 0; q < 12; ++q) {
      float e0 = (v[2*q]   - mean) * inv * ga[2*q]   + ba[2*q];
      float e1 = (v[2*q+1] - mean) * inv * ga[2*q+1] + ba[2*q+1];
      unsigned short h0 = f2bf(e0), h1 = f2bf(e1);
      hi[q] = (unsigned)h0 | ((unsigned)h1 << 16);
      lo[q] = pack2(e0 - bf2f(h0), e1 - bf2f(h1));
    }
#pragma unroll
    for (int q = 12; q < 16; ++q) { hi[q] = 0u; lo[q] = 0u; }
#pragma unroll
    for (int q4 = 0; q4 < 4; ++q4) {
      ((uint4*)dh)[q4] = make_uint4(hi[4*q4], hi[4*q4+1], hi[4*q4+2], hi[4*q4+3]);
      ((uint4*)dl)[q4] = make_uint4(lo[4*q4], lo[4*q4+1], lo[4*q4+2], lo[4*q4+3]);
    }
  }
}

// single-gate variant (for u)
__global__ void k_emb(const float* __restrict__ node_emb,
                      const float* __restrict__ time_emb,
                      const float* __restrict__ gA, const float* __restrict__ bA,
                      unsigned* __restrict__ emb_hi, unsigned* __restrict__ emb_lo) {
  int idx = blockIdx.x * 256 + threadIdx.x;
  int n  = idx & (NN - 1);
  int bt = idx >> 11;
  float v[DEE];
  float mean = 0.f;
#pragma unroll
  for (int d = 0; d < DEE; ++d) {
    v[d] = node_emb[n * DEE + d] + time_emb[bt * DEE + d];
    mean += v[d];
  }
  mean *= (1.f / DEE);
  float var = 0.f;
#pragma unroll
  for (int d = 0; d < DEE; ++d) { float u = v[d] - mean; var += u * u; }
  var *= (1.f / DEE);
  float inv = 1.f / sqrtf(var + 1e-12f);
  unsigned hi[16], lo[16];
#pragma unroll
  for (int q = 0; q < 12; ++q) {
    float e0 = (v[2*q]   - mean) * inv * gA[2*q]   + bA[2*q];
    float e1 = (v[2*q+1] - mean) * inv * gA[2*q+1] + bA[2*q+1];
    unsigned short h0 = f2bf(e0), h1 = f2bf(e1);
    hi[q] = (unsigned)h0 | ((unsigned)h1 << 16);
    lo[q] = pack2(e0 - bf2f(h0), e1 - bf2f(h1));
  }
#pragma unroll
  for (int q = 12; q < 16; ++q) { hi[q] = 0u; lo[q] = 0u; }
  unsigned* dh = emb_hi + (size_t)idx * 16;
  unsigned* dl = emb_lo + (size_t)idx * 16;
#pragma unroll
  for (int q4 = 0; q4 < 4; ++q4) {
    ((uint4*)dh)[q4] = make_uint4(hi[4*q4], hi[4*q4+1], hi[4*q4+2], hi[4*q4+3]);
    ((uint4*)dl)[q4] = make_uint4(lo[4*q4], lo[4*q4+1], lo[4*q4+2], lo[4*q4+3]);
  }
}

// XCD-aware block swizzle: each XCD (id = L%8) sees only bt = {2j, 2j+1}
__device__ __forceinline__ void swz(int L, int& bt, int& rbase) {
  bt = (L & 7) * 2 + ((L >> 3) & 1);
  rbase = (L >> 4) * RT;
}

// ---------------- fused graph attention, z+r merged ----------------------
__global__ __launch_bounds__(256, 3) void k_flash_zr(
    const unsigned* __restrict__ ehZ, const unsigned* __restrict__ elZ,
    const unsigned* __restrict__ ehR, const unsigned* __restrict__ elR,
    const float* __restrict__ x, const float* __restrict__ states,
    unsigned short* __restrict__ AxZ, unsigned short* __restrict__ AxR) {
  __shared__ unsigned short s_em[2][2][MT * 40];   // [gate][hi/lo][m][k] stride 40
  __shared__ unsigned short s_xt[2 * 6 * 64 * 8];  // [kc][nt][lane][8]
  __shared__ unsigned short s_p[2][RT * 72];

  const int t = threadIdx.x;
  const int w = t >> 6, l = t & 63;
  const int lane_lo = l & 15, lane_hi = l >> 4;
  const int k0 = lane_hi * 8;
  int bt, rbase; swz(blockIdx.x, bt, rbase);
  const int b = bt >> 1, tt = bt & 1;

  const unsigned* eh[2] = {ehZ, ehR};
  const unsigned* el[2] = {elZ, elR};

  // ---- A fragments straight from global (layout is fragment-compatible) ----
  short8 a_hi[2], a_lo[2];
  {
    const size_t row = (size_t)bt * NN + rbase + w * 16 + lane_lo;
#pragma unroll
    for (int g = 0; g < 2; ++g) {
      a_hi[g] = *(const short8*)((const short*)eh[g] + row * 32 + k0);
      a_lo[g] = *(const short8*)((const short*)el[g] + row * 32 + k0);
    }
  }

  // ---- prefetch registers (em tiles + xin) ----
  unsigned pem[2][2][4];
  unsigned pxw[4], psw[8];
  auto preload = [&](int mbase) {
#pragma unroll
    for (int g = 0; g < 2; ++g) {
      const unsigned* sh = eh[g] + ((size_t)bt * NN + mbase) * 16;
      const unsigned* sl = el[g] + ((size_t)bt * NN + mbase) * 16;
#pragma unroll
      for (int q = 0; q < 4; ++q) {
        int e = t + 256 * q;
        pem[g][0][q] = sh[e];
        pem[g][1][q] = sl[e];
      }
    }
#pragma unroll
    for (int q = 0; q < 4; ++q) {
      int e = t + 256 * q;
      int m = (e >> 5) * 2, c = e & 31;
      const float* xp = &x[((size_t)bt * NN + mbase + m) * DII + c];
      pxw[q] = pack2(xp[0], xp[DII]);
    }
#pragma unroll
    for (int q = 0; q < 8; ++q) {
      int e = t + 256 * q;
      int m = (e >> 6) * 2, d = e & 63;
      size_t sidx = (((size_t)b * THH + (THH - KTT) + tt) * NN + mbase + m) * DHD + d;
      psw[q] = pack2(states[sidx], states[sidx + DHD]);
    }
  };
  preload(0);

  float m_run[2][4], l_run[2][4];
#pragma unroll
  for (int g = 0; g < 2; ++g)
#pragma unroll
    for (int i = 0; i < 4; ++i) { m_run[g][i] = -1e30f; l_run[g][i] = 0.f; }
  f32x4 acc[2][6];
#pragma unroll
  for (int g = 0; g < 2; ++g)
#pragma unroll
    for (int j = 0; j < 6; ++j) acc[g][j] = (f32x4){0.f, 0.f, 0.f, 0.f};

  for (int mt = 0; mt < NN / MT; ++mt) {
    __syncthreads();
    // ---- write prefetched regs -> LDS ----
#pragma unroll
    for (int g = 0; g < 2; ++g)
#pragma unroll
      for (int q = 0; q < 4; ++q) {
        int e = t + 256 * q;
        int node = e >> 4, off = e & 15;
        ((unsigned*)s_em[g][0])[node * 20 + off] = pem[g][0][q];
        ((unsigned*)s_em[g][1])[node * 20 + off] = pem[g][1][q];
      }
#pragma unroll
    for (int q = 0; q < 4; ++q) {
      int e = t + 256 * q;
      int m2 = e >> 5, c = e & 31;
      int kc = m2 >> 4, g2 = (m2 >> 2) & 3, wd = m2 & 3;
      int nt = c >> 4, ll = c & 15;
      ((unsigned*)s_xt)[((kc * 6 + nt) * 64 + (ll + g2 * 16)) * 4 + wd] = pxw[q];
    }
#pragma unroll
    for (int q = 0; q < 8; ++q) {
      int e = t + 256 * q;
      int m2 = e >> 6, d = e & 63;
      int c = DII + d;
      int kc = m2 >> 4, g2 = (m2 >> 2) & 3, wd = m2 & 3;
      int nt = c >> 4, ll = c & 15;
      ((unsigned*)s_xt)[((kc * 6 + nt) * 64 + (ll + g2 * 16)) * 4 + wd] = psw[q];
    }
    __syncthreads();
    if (mt + 1 < NN / MT) preload((mt + 1) * MT);   // overlap with compute

    // ---- scores for both gates ----
    f32x4 sc[2][4];
#pragma unroll
    for (int g = 0; g < 2; ++g)
#pragma unroll
      for (int nt = 0; nt < 4; ++nt) {
        const short8 b_hi = *(const short8*)&s_em[g][0][(nt * 16 + lane_lo) * 40 + k0];
        const short8 b_lo = *(const short8*)&s_em[g][1][(nt * 16 + lane_lo) * 40 + k0];
        f32x4 c0 = (f32x4){0.f, 0.f, 0.f, 0.f};
        c0 = MFMA16(a_hi[g], b_hi, c0);
        c0 = MFMA16(a_hi[g], b_lo, c0);
        c0 = MFMA16(a_lo[g], b_hi, c0);
        sc[g][nt] = c0;
      }
    // ---- online softmax (per gate) ----
#pragma unroll
    for (int g = 0; g < 2; ++g) {
      float alpha[4], nm[4];
#pragma unroll
      for (int i = 0; i < 4; ++i) {
        float mx = fmaxf(fmaxf(sc[g][0][i], sc[g][1][i]),
                         fmaxf(sc[g][2][i], sc[g][3][i]));
        mx = fmaxf(mx, __shfl_xor(mx, 1, 64));
        mx = fmaxf(mx, __shfl_xor(mx, 2, 64));
        mx = fmaxf(mx, __shfl_xor(mx, 4, 64));
        mx = fmaxf(mx, __shfl_xor(mx, 8, 64));
        nm[i] = fmaxf(m_run[g][i], mx);
        alpha[i] = __expf(m_run[g][i] - nm[i]);
        m_run[g][i] = nm[i];
      }
      float rs[4] = {0.f, 0.f, 0.f, 0.f};
#pragma unroll
      for (int nt = 0; nt < 4; ++nt)
#pragma unroll
        for (int i = 0; i < 4; ++i) {
          float pv = __expf(sc[g][nt][i] - nm[i]);
          s_p[g][(w * 16 + lane_hi * 4 + i) * 72 + nt * 16 + lane_lo] = f2bf(pv);
          rs[i] += pv;
        }
#pragma unroll
      for (int i = 0; i < 4; ++i) {
        float s = rs[i];
        s += __shfl_xor(s, 1, 64);
        s += __shfl_xor(s, 2, 64);
        s += __shfl_xor(s, 4, 64);
        s += __shfl_xor(s, 8, 64);
        l_run[g][i] = l_run[g][i] * alpha[i] + s;
      }
#pragma unroll
      for (int j = 0; j < 6; ++j)
#pragma unroll
        for (int i = 0; i < 4; ++i) acc[g][j][i] *= alpha[i];
    }
    // ---- PV for both gates, sharing xin fragments ----
    const short8 paZ0 = *(const short8*)&s_p[0][(w * 16 + lane_lo) * 72 + k0];
    const short8 paZ1 = *(const short8*)&s_p[0][(w * 16 + lane_lo) * 72 + 32 + k0];
    const short8 paR0 = *(const short8*)&s_p[1][(w * 16 + lane_lo) * 72 + k0];
    const short8 paR1 = *(const short8*)&s_p[1][(w * 16 + lane_lo) * 72 + 32 + k0];
#pragma unroll
    for (int nt2 = 0; nt2 < 6; ++nt2) {
      const short8 xb0 = *(const short8*)&s_xt[((0 * 6 + nt2) * 64 + l) * 8];
      const short8 xb1 = *(const short8*)&s_xt[((1 * 6 + nt2) * 64 + l) * 8];
      acc[0][nt2] = MFMA16(paZ0, xb0, acc[0][nt2]);
      acc[0][nt2] = MFMA16(paZ1, xb1, acc[0][nt2]);
      acc[1][nt2] = MFMA16(paR0, xb0, acc[1][nt2]);
      acc[1][nt2] = MFMA16(paR1, xb1, acc[1][nt2]);
    }
  }
  // ---- epilogue ----
#pragma unroll
  for (int g = 0; g < 2; ++g) {
    unsigned short* Ax = g ? AxR : AxZ;
    float invl[4];
#pragma unroll
    for (int i = 0; i < 4; ++i) invl[i] = 1.f / l_run[g][i];
#pragma unroll
    for (int nt2 = 0; nt2 < 6; ++nt2)
#pragma unroll
      for (int i = 0; i < 4; ++i) {
        size_t o = ((size_t)bt * NN + rbase + w * 16 + lane_hi * 4 + i) * CC +
                   nt2 * 16 + lane_lo;
        Ax[o] = f2bf(acc[g][nt2][i] * invl[i]);
      }
  }
}

// ---------------- single-gate flash (u): xin = concat(x, z*state) ------------
__global__ __launch_bounds__(256, 4) void k_flash_u(
    const unsigned* __restrict__ emb_hi, const unsigned* __restrict__ emb_lo,
    const float* __restrict__ x, const float* __restrict__ states,
    const float* __restrict__ zbuf, unsigned short* __restrict__ Ax) {
  __shared__ unsigned short s_em_hi[MT * 40];
  __shared__ unsigned short s_em_lo[MT * 40];
  __shared__ unsigned short s_xt[2 * 6 * 64 * 8];
  __shared__ unsigned short s_p[RT * 72];

  const int t = threadIdx.x;
  const int w = t >> 6, l = t & 63;
  const int lane_lo = l & 15, lane_hi = l >> 4;
  const int k0 = lane_hi * 8;
  int bt, rbase; swz(blockIdx.x, bt, rbase);
  const int b = bt >> 1, tt = bt & 1;

  short8 a_hi, a_lo;
  {
    const size_t row = (size_t)bt * NN + rbase + w * 16 + lane_lo;
    a_hi = *(const short8*)((const short*)emb_hi + row * 32 + k0);
    a_lo = *(const short8*)((const short*)emb_lo + row * 32 + k0);
  }

  unsigned pemh[4], peml[4], pxw[4], psw[8];
  auto preload = [&](int mbase) {
    const unsigned* sh = emb_hi + ((size_t)bt * NN + mbase) * 16;
    const unsigned* sl = emb_lo + ((size_t)bt * NN + mbase) * 16;
#pragma unroll
    for (int q = 0; q < 4; ++q) {
      int e = t + 256 * q;
      pemh[q] = sh[e];
      peml[q] = sl[e];
    }
#pragma unroll
    for (int q = 0; q < 4; ++q) {
      int e = t + 256 * q;
      int m = (e >> 5) * 2, c = e & 31;
      const float* xp = &x[((size_t)bt * NN + mbase + m) * DII + c];
      pxw[q] = pack2(xp[0], xp[DII]);
    }
#pragma unroll
    for (int q = 0; q < 8; ++q) {
      int e = t + 256 * q;
      int m = (e >> 6) * 2, d = e & 63;
      size_t sidx = (((size_t)b * THH + (THH - KTT) + tt) * NN + mbase + m) * DHD + d;
      size_t zidx = ((size_t)bt * NN + mbase + m) * DHD + d;
      psw[q] = pack2(states[sidx] * zbuf[zidx], states[sidx + DHD] * zbuf[zidx + DHD]);
    }
  };
  preload(0);

  float m_run[4], l_run[4];
#pragma unroll
  for (int i = 0; i < 4; ++i) { m_run[i] = -1e30f; l_run[i] = 0.f; }
  f32x4 acc[6];
#pragma unroll
  for (int j = 0; j < 6; ++j) acc[j] = (f32x4){0.f, 0.f, 0.f, 0.f};

  for (int mt = 0; mt < NN / MT; ++mt) {
    __syncthreads();
#pragma unroll
    for (int q = 0; q < 4; ++q) {
      int e = t + 256 * q;
      int node = e >> 4, off = e & 15;
      ((unsigned*)s_em_hi)[node * 20 + off] = pemh[q];
      ((unsigned*)s_em_lo)[node * 20 + off] = peml[q];
    }
#pragma unroll
    for (int q = 0; q < 4; ++q) {
      int e = t + 256 * q;
      int m2 = e >> 5, c = e & 31;
      int kc = m2 >> 4, g2 = (m2 >> 2) & 3, wd = m2 & 3;
      int nt = c >> 4, ll = c & 15;
      ((unsigned*)s_xt)[((kc * 6 + nt) * 64 + (ll + g2 * 16)) * 4 + wd] = pxw[q];
    }
#pragma unroll
    for (int q = 0; q < 8; ++q) {
      int e = t + 256 * q;
      int m2 = e >> 6, d = e & 63;
      int c = DII + d;
      int kc = m2 >> 4, g2 = (m2 >> 2) & 3, wd = m2 & 3;
      int nt = c >> 4, ll = c & 15;
      ((unsigned*)s_xt)[((kc * 6 + nt) * 64 + (ll + g2 * 16)) * 4 + wd] = psw[q];
    }
    __syncthreads();
    if (mt + 1 < NN / MT) preload((mt + 1) * MT);

    f32x4 sc[4];
#pragma unroll
    for (int nt = 0; nt < 4; ++nt) {
      const short8 b_hi = *(const short8*)&s_em_hi[(nt * 16 + lane_lo) * 40 + k0];
      const short8 b_lo = *(const short8*)&s_em_lo[(nt * 16 + lane_lo) * 40 + k0];
      f32x4 c0 = (f32x4){0.f, 0.f, 0.f, 0.f};
      c0 = MFMA16(a_hi, b_hi, c0);
      c0 = MFMA16(a_hi, b_lo, c0);
      c0 = MFMA16(a_lo, b_hi, c0);
      sc[nt] = c0;
    }
    float alpha[4], nm[4];
#pragma unroll
    for (int i = 0; i < 4; ++i) {
      float mx = fmaxf(fmaxf(sc[0][i], sc[1][i]), fmaxf(sc[2][i], sc[3][i]));
      mx = fmaxf(mx, __shfl_xor(mx, 1, 64));
      mx = fmaxf(mx, __shfl_xor(mx, 2, 64));
      mx = fmaxf(mx, __shfl_xor(mx, 4, 64));
      mx = fmaxf(mx, __shfl_xor(mx, 8, 64));
      nm[i] = fmaxf(m_run[i], mx);
      alpha[i] = __expf(m_run[i] - nm[i]);
      m_run[i] = nm[i];
    }
    float rs[4] = {0.f, 0.f, 0.f, 0.f};
#pragma unroll
    for (int nt = 0; nt < 4; ++nt)
#pragma unroll
      for (int i = 0; i < 4; ++i) {
        float pv = __expf(sc[nt][i] - nm[i]);
        s_p[(w * 16 + lane_hi * 4 + i) * 72 + nt * 16 + lane_lo] = f2bf(pv);
        rs[i] += pv;
      }
#pragma unroll
    for (int i = 0; i < 4; ++i) {
      float s = rs[i];
      s += __shfl_xor(s, 1, 64);
      s += __shfl_xor(s, 2, 64);
      s += __shfl_xor(s, 4, 64);
      s += __shfl_xor(s, 8, 64);
      l_run[i] = l_run[i] * alpha[i] + s;
    }
#pragma unroll
    for (int j = 0; j < 6; ++j)
#pragma unroll
      for (int i = 0; i < 4; ++i) acc[j][i] *= alpha[i];
    const short8 pa0 = *(const short8*)&s_p[(w * 16 + lane_lo) * 72 + k0];
    const short8 pa1 = *(const short8*)&s_p[(w * 16 + lane_lo) * 72 + 32 + k0];
#pragma unroll
    for (int nt2 = 0; nt2 < 6; ++nt2) {
      const short8 xb0 = *(const short8*)&s_xt[((0 * 6 + nt2) * 64 + l) * 8];
      const short8 xb1 = *(const short8*)&s_xt[((1 * 6 + nt2) * 64 + l) * 8];
      acc[nt2] = MFMA16(pa0, xb0, acc[nt2]);
      acc[nt2] = MFMA16(pa1, xb1, acc[nt2]);
    }
  }
  float invl[4];
#pragma unroll
  for (int i = 0; i < 4; ++i) invl[i] = 1.f / l_run[i];
#pragma unroll
  for (int nt2 = 0; nt2 < 6; ++nt2)
#pragma unroll
    for (int i = 0; i < 4; ++i) {
      size_t o = ((size_t)bt * NN + rbase + w * 16 + lane_hi * 4 + i) * CC +
                 nt2 * 16 + lane_lo;
      Ax[o] = f2bf(acc[nt2][i] * invl[i]);
    }
}

// ------------- per-node weight matmul, NB=4 nodes/block, MFMA stage-2 --------
// g[bt,n,o] = xg[bt,n,:] @ (ne[n] @ Wp)[:,o] + te[bt] @ bp[:,o]
template <int MODE>
__global__ __launch_bounds__(256, 2) void k_nodemm(
    const float* __restrict__ x, const float* __restrict__ states,
    const float* __restrict__ zbuf, const unsigned short* __restrict__ Ax,
    const float* __restrict__ node_emb, const float* __restrict__ time_emb,
    const float* __restrict__ Wp, const float* __restrict__ bp,
    float* __restrict__ g) {
  // s_W: bf16 B-fragments for one ki-half: [n][(kc*4+ot)*64 + lane][8]
  __shared__ unsigned short s_W[4 * 6144];    // 49152 B
  __shared__ unsigned short s_xg[64 * 200];   // [(n*16+bt)][ki], 25600 B
  __shared__ float s_bias[BT * DHD];          // 4096 B

  const int t = threadIdx.x;
  const int w = t >> 6, l = t & 63;
  const int n0 = blockIdx.x * 4;

  // node_emb for the block's 4 nodes (block-uniform)
  float ne[4][DEE];
#pragma unroll
  for (int n = 0; n < 4; ++n)
#pragma unroll
    for (int d = 0; d < DEE; ++d) ne[n][d] = node_emb[(n0 + n) * DEE + d];

  // bias: s_bias[bt][o] = sum_d te[bt,d] * bp[d,o]
#pragma unroll
  for (int q = 0; q < 4; ++q) {
    int e = t + 256 * q;
    int bt = e >> 6, o = e & 63;
    float a = 0.f;
#pragma unroll
    for (int d = 0; d < DEE; ++d) a += time_emb[bt * DEE + d] * bp[d * DHD + o];
    s_bias[e] = a;
  }
  // xg staging (bf16): rows = [n][bt], cols ki = [x(32) | state(64) | Ax(96)]
#pragma unroll
  for (int q = 0; q < 48; ++q) {
    int e = t + 256 * q;                 // row*192 + ki
    int row = e / 192, ki = e - row * 192;
    int n = n0 + (row >> 4), bt = row & 15;
    unsigned short hv;
    if (ki < DII) {
      hv = f2bf(x[((size_t)bt * NN + n) * DII + ki]);
    } else if (ki < CC) {
      float v = states[(((size_t)(bt >> 1) * THH + (THH - KTT) + (bt & 1)) * NN + n) * DHD + (ki - DII)];
      if (MODE == 1) v *= zbuf[((size_t)bt * NN + n) * DHD + (ki - DII)];
      hv = f2bf(v);
    } else {
      hv = Ax[((size_t)bt * NN + n) * CC + (ki - CC)];
    }
    s_xg[row * 200 + ki] = hv;
  }
  __syncthreads();

  f32x4 acc[4];
#pragma unroll
  for (int ot = 0; ot < 4; ++ot) acc[ot] = (f32x4){0.f, 0.f, 0.f, 0.f};

  const int o0 = (t & 15) * 4;
  for (int pass = 0; pass < 2; ++pass) {
    // ---- weight-gen (fp32) for ki in [pass*96, pass*96+96), all 4 nodes ----
#pragma unroll
    for (int it = 0; it < 6; ++it) {
      const int j = pass * 6144 + it * 1024 + t * 4;   // col-quad in Wp
      const int ki = j >> 6;
      float f[4][4];
#pragma unroll
      for (int n = 0; n < 4; ++n)
#pragma unroll
        for (int c = 0; c < 4; ++c) f[n][c] = 0.f;
#pragma unroll
      for (int d = 0; d < DEE; ++d) {
        const float4 wq = *(const float4*)&Wp[(size_t)d * 12288 + j];
#pragma unroll
        for (int n = 0; n < 4; ++n) {
          f[n][0] = fmaf(ne[n][d], wq.x, f[n][0]);
          f[n][1] = fmaf(ne[n][d], wq.y, f[n][1]);
          f[n][2] = fmaf(ne[n][d], wq.z, f[n][2]);
          f[n][3] = fmaf(ne[n][d], wq.w, f[n][3]);
        }
      }
      const int kc = (ki >> 5) - pass * 3;
      const int kg = (ki >> 3) & 3, jj = ki & 7;
#pragma unroll
      for (int c = 0; c < 4; ++c) {
        const int oc = o0 + c;
        const int addr = ((kc * 4 + (oc >> 4)) * 64 + ((oc & 15) + kg * 16)) * 8 + jj;
#pragma unroll
        for (int n = 0; n < 4; ++n) s_W[n * 6144 + addr] = f2bf(f[n][c]);
      }
    }
    __syncthreads();
    // ---- stage-2 MFMA: wave w <-> node n0+w ----
#pragma unroll
    for (int kc = 0; kc < 3; ++kc) {
      const short8 A = *(const short8*)
          &s_xg[(w * 16 + (l & 15)) * 200 + pass * 96 + kc * 32 + (l >> 4) * 8];
#pragma unroll
      for (int ot = 0; ot < 4; ++ot) {
        const short8 Bv = *(const short8*)&s_W[w * 6144 + ((kc * 4 + ot) * 64 + l) * 8];
        acc[ot] = MFMA16(A, Bv, acc[ot]);
      }
    }
    __syncthreads();
  }
  // ---- epilogue: D row=(l>>4)*4+i = bt, col=ot*16+(l&15) = o ----
  const int n = n0 + w;
#pragma unroll
  for (int ot = 0; ot < 4; ++ot)
#pragma unroll
    for (int i = 0; i < 4; ++i) {
      const int bt = (l >> 4) * 4 + i;
      const int o = ot * 16 + (l & 15);
      g[((size_t)bt * NN + n) * DHD + o] = acc[ot][i] + s_bias[bt * DHD + o];
    }
}

// --------------------- LN + tiny MHA + activation / gate ---------------------
__device__ __forceinline__ float wsum64(float v) {
#pragma unroll
  for (int off = 32; off > 0; off >>= 1) v += __shfl_xor(v, off, 64);
  return v;
}
__device__ __forceinline__ float hsum16(float v) {
  v += __shfl_xor(v, 8, 64);
  v += __shfl_xor(v, 4, 64);
  v += __shfl_xor(v, 2, 64);
  v += __shfl_xor(v, 1, 64);
  return v;
}

template <int MODE>
__global__ void k_attn(const float* __restrict__ g,
                       const float* __restrict__ states,
                       const float* __restrict__ lnOg,
                       const float* __restrict__ lnOb,
                       const float* __restrict__ rbuf,
                       float* __restrict__ dst) {
  const int lane = threadIdx.x & 63;
  const int unit = blockIdx.x * 4 + (threadIdx.x >> 6);  // b*NN + n
  const int b = unit >> 11;
  const int n = unit & (NN - 1);

  float kv[THH];
#pragma unroll
  for (int s = 0; s < THH; ++s)
    kv[s] = states[(((size_t)b * THH + s) * NN + n) * DHD + lane];
  const float go = lnOg[lane], bo = lnOb[lane];

#pragma unroll
  for (int tt = 0; tt < KTT; ++tt) {
    const size_t oi = (((size_t)b * KTT + tt) * NN + n) * DHD + lane;
    const float gval = g[oi];
    float mean = wsum64(gval) * (1.f / 64.f);
    float dv = gval - mean;
    float var = wsum64(dv * dv) * (1.f / 64.f);
    float q = dv * (1.f / sqrtf(var + 1e-5f)) * go + bo;
    float sc[THH];
#pragma unroll
    for (int s = 0; s < THH; ++s) sc[s] = hsum16(q * kv[s]) * 0.25f;
    float mx = sc[0];
#pragma unroll
    for (int s = 1; s < THH; ++s) mx = fmaxf(mx, sc[s]);
    float sum = 0.f;
#pragma unroll
    for (int s = 0; s < THH; ++s) { sc[s] = __expf(sc[s] - mx); sum += sc[s]; }
    float o = 0.f;
#pragma unroll
    for (int s = 0; s < THH; ++s) o += sc[s] * kv[s];
    o /= sum;
    const float val = gval + o;
    if (MODE == 0) {
      dst[oi] = 1.f / (1.f + __expf(-val));
    } else {
      const float hc = tanhf(val);
      const float stl =
          states[(((size_t)b * THH + (THH - KTT) + tt) * NN + n) * DHD + lane];
      const float rr = rbuf[oi];
      dst[oi] = rr * stl + (1.f - rr) * hc;
    }
  }
}

extern "C" void kernel_launch(void* const* d_in, const int* in_sizes, int n_in,
                              void* d_out, int out_size, void* d_ws, size_t ws_size,
                              hipStream_t stream) {
  const float* x        = (const float*)d_in[0];
  const float* states   = (const float*)d_in[1];
  const float* node_emb = (const float*)d_in[2];
  const float* time_emb = (const float*)d_in[3];

  unsigned char* wsb = (unsigned char*)d_ws;
  unsigned*       ehZ = (unsigned*)(wsb);              // 2MB each
  unsigned*       elZ = (unsigned*)(wsb + (2u << 20));
  unsigned*       ehR = (unsigned*)(wsb + (4u << 20));
  unsigned*       elR = (unsigned*)(wsb + (6u << 20));
  unsigned short* AxZ = (unsigned short*)(wsb + (8u << 20));   // 6MB
  unsigned short* AxR = (unsigned short*)(wsb + (14u << 20));  // 6MB
  float*          gb  = (float*)(wsb + (20u << 20));           // 8MB
  float*          zb  = (float*)(wsb + (28u << 20));           // 8MB
  float*          rb  = (float*)(wsb + (36u << 20));           // 8MB
  float* outp = (float*)d_out;

  struct Gate { const float *W, *bias, *lAg, *lAb, *lOg, *lOb; };
  auto G = [&](int i) {
    return Gate{(const float*)d_in[i],     (const float*)d_in[i + 1],
                (const float*)d_in[i + 2], (const float*)d_in[i + 3],
                (const float*)d_in[i + 4], (const float*)d_in[i + 5]};
  };
  Gate gz = G(4), gr = G(10), gu = G(16);

  const int gridE = BT * NN / 256;
  const int gridA = BB * NN / 4;
  const int gridF = (NN / RT) * BT;   // 512, swizzled inside
  const int gridN = NN / 4;           // 512

  // ---- z and r gates (shared xin) ----
  k_emb2<<<gridE, 256, 0, stream>>>(node_emb, time_emb, gz.lAg, gz.lAb,
                                    gr.lAg, gr.lAb, ehZ, elZ, ehR, elR);
  k_flash_zr<<<gridF, 256, 0, stream>>>(ehZ, elZ, ehR, elR, x, states, AxZ, AxR);
  k_nodemm<0><<<gridN, 256, 0, stream>>>(x, states, nullptr, AxZ, node_emb,
                                         time_emb, gz.W, gz.bias, gb);
  k_attn<0><<<gridA, 256, 0, stream>>>(gb, states, gz.lOg, gz.lOb, nullptr, zb);
  k_nodemm<0><<<gridN, 256, 0, stream>>>(x, states, nullptr, AxR, node_emb,
                                         time_emb, gr.W, gr.bias, gb);
  k_attn<0><<<gridA, 256, 0, stream>>>(gb, states, gr.lOg, gr.lOb, nullptr, rb);
  // ---- u gate + final combine ----
  k_emb<<<gridE, 256, 0, stream>>>(node_emb, time_emb, gu.lAg, gu.lAb, ehZ, elZ);
  k_flash_u<<<gridF, 256, 0, stream>>>(ehZ, elZ, x, states, zb, AxZ);
  k_nodemm<1><<<gridN, 256, 0, stream>>>(x, states, zb, AxZ, node_emb, time_emb,
                                         gu.W, gu.bias, gb);
  k_attn<1><<<gridA, 256, 0, stream>>>(gb, states, gu.lOg, gu.lOb, rb, outp);
}

// Round 5
// 770.130 us; speedup vs baseline: 1.5686x; 1.5686x over previous
//
#include <hip/hip_runtime.h>
#include <math.h>

#define BB  8
#define KTT 2
#define THH 12
#define NN  2048
#define DII 32
#define DHD 64
#define DEE 24
#define CC  96
#define BT  16      // BB*KTT
#define RT  64      // row tile
#define MT  64      // m tile

typedef __attribute__((ext_vector_type(8))) short short8;   // 8 bf16 = 4 VGPRs
typedef __attribute__((ext_vector_type(4))) float f32x4;

#define MFMA16(a, b, c) __builtin_amdgcn_mfma_f32_16x16x32_bf16(a, b, c, 0, 0, 0)

__device__ __forceinline__ unsigned short f2bf(float f) {
  unsigned u = __builtin_bit_cast(unsigned, f);
  u += 0x7FFFu + ((u >> 16) & 1u);
  return (unsigned short)(u >> 16);
}
__device__ __forceinline__ float bf2f(unsigned short h) {
  return __builtin_bit_cast(float, ((unsigned)h) << 16);
}
__device__ __forceinline__ unsigned pack2(float a, float b) {
  return (unsigned)f2bf(a) | ((unsigned)f2bf(b) << 16);
}

// ---- LN(node_emb + time_emb)*g + b (eps 1e-12) -> bf16 hi/lo, two gates ----
__global__ void k_emb2(const float* __restrict__ node_emb,
                       const float* __restrict__ time_emb,
                       const float* __restrict__ gZ, const float* __restrict__ bZ,
                       const float* __restrict__ gR, const float* __restrict__ bR,
                       unsigned* __restrict__ ehZ, unsigned* __restrict__ elZ,
                       unsigned* __restrict__ ehR, unsigned* __restrict__ elR) {
  int idx = blockIdx.x * 256 + threadIdx.x;   // bt*NN + n
  int n  = idx & (NN - 1);
  int bt = idx >> 11;
  float v[DEE];
  float mean = 0.f;
#pragma unroll
  for (int d = 0; d < DEE; ++d) {
    v[d] = node_emb[n * DEE + d] + time_emb[bt * DEE + d];
    mean += v[d];
  }
  mean *= (1.f / DEE);
  float var = 0.f;
#pragma unroll
  for (int d = 0; d < DEE; ++d) { float u = v[d] - mean; var += u * u; }
  var *= (1.f / DEE);
  float inv = 1.f / sqrtf(var + 1e-12f);
#pragma unroll
  for (int gate = 0; gate < 2; ++gate) {
    const float* ga = gate ? gR : gZ;
    const float* ba = gate ? bR : bZ;
    unsigned* dh = (gate ? ehR : ehZ) + (size_t)idx * 16;
    unsigned* dl = (gate ? elR : elZ) + (size_t)idx * 16;
    unsigned hi[16], lo[16];
#pragma unroll
    for (int q = 0; q < 12; ++q) {
      float e0 = (v[2*q]   - mean) * inv * ga[2*q]   + ba[2*q];
      float e1 = (v[2*q+1] - mean) * inv * ga[2*q+1] + ba[2*q+1];
      unsigned short h0 = f2bf(e0), h1 = f2bf(e1);
      hi[q] = (unsigned)h0 | ((unsigned)h1 << 16);
      lo[q] = pack2(e0 - bf2f(h0), e1 - bf2f(h1));
    }
#pragma unroll
    for (int q = 12; q < 16; ++q) { hi[q] = 0u; lo[q] = 0u; }
#pragma unroll
    for (int q4 = 0; q4 < 4; ++q4) {
      ((uint4*)dh)[q4] = make_uint4(hi[4*q4], hi[4*q4+1], hi[4*q4+2], hi[4*q4+3]);
      ((uint4*)dl)[q4] = make_uint4(lo[4*q4], lo[4*q4+1], lo[4*q4+2], lo[4*q4+3]);
    }
  }
}

// single-gate variant (for u)
__global__ void k_emb(const float* __restrict__ node_emb,
                      const float* __restrict__ time_emb,
                      const float* __restrict__ gA, const float* __restrict__ bA,
                      unsigned* __restrict__ emb_hi, unsigned* __restrict__ emb_lo) {
  int idx = blockIdx.x * 256 + threadIdx.x;
  int n  = idx & (NN - 1);
  int bt = idx >> 11;
  float v[DEE];
  float mean = 0.f;
#pragma unroll
  for (int d = 0; d < DEE; ++d) {
    v[d] = node_emb[n * DEE + d] + time_emb[bt * DEE + d];
    mean += v[d];
  }
  mean *= (1.f / DEE);
  float var = 0.f;
#pragma unroll
  for (int d = 0; d < DEE; ++d) { float u = v[d] - mean; var += u * u; }
  var *= (1.f / DEE);
  float inv = 1.f / sqrtf(var + 1e-12f);
  unsigned hi[16], lo[16];
#pragma unroll
  for (int q = 0; q < 12; ++q) {
    float e0 = (v[2*q]   - mean) * inv * gA[2*q]   + bA[2*q];
    float e1 = (v[2*q+1] - mean) * inv * gA[2*q+1] + bA[2*q+1];
    unsigned short h0 = f2bf(e0), h1 = f2bf(e1);
    hi[q] = (unsigned)h0 | ((unsigned)h1 << 16);
    lo[q] = pack2(e0 - bf2f(h0), e1 - bf2f(h1));
  }
#pragma unroll
  for (int q = 12; q < 16; ++q) { hi[q] = 0u; lo[q] = 0u; }
  unsigned* dh = emb_hi + (size_t)idx * 16;
  unsigned* dl = emb_lo + (size_t)idx * 16;
#pragma unroll
  for (int q4 = 0; q4 < 4; ++q4) {
    ((uint4*)dh)[q4] = make_uint4(hi[4*q4], hi[4*q4+1], hi[4*q4+2], hi[4*q4+3]);
    ((uint4*)dl)[q4] = make_uint4(lo[4*q4], lo[4*q4+1], lo[4*q4+2], lo[4*q4+3]);
  }
}

// XCD-aware block swizzle: each XCD (id = L%8) sees only bt = {2j, 2j+1}
__device__ __forceinline__ void swz(int L, int& bt, int& rbase) {
  bt = (L & 7) * 2 + ((L >> 3) & 1);
  rbase = (L >> 4) * RT;
}

// ---------------- fused graph attention, z+r merged ----------------------
// NOTE: launch_bounds must stay (256,2): (256,3) caps VGPR at ~84 -> K-loop
// scratch spills (measured round 4: WRITE_SIZE 12MB -> 200MB, dur 158->414us).
__global__ __launch_bounds__(256, 2) void k_flash_zr(
    const unsigned* __restrict__ ehZ, const unsigned* __restrict__ elZ,
    const unsigned* __restrict__ ehR, const unsigned* __restrict__ elR,
    const float* __restrict__ x, const float* __restrict__ states,
    unsigned short* __restrict__ AxZ, unsigned short* __restrict__ AxR) {
  __shared__ unsigned short s_em[2][2][MT * 40];   // [gate][hi/lo][m][k] stride 40
  __shared__ unsigned short s_xt[2 * 6 * 64 * 8];  // [kc][nt][lane][8]
  __shared__ unsigned short s_p[2][RT * 72];

  const int t = threadIdx.x;
  const int w = t >> 6, l = t & 63;
  const int lane_lo = l & 15, lane_hi = l >> 4;
  const int k0 = lane_hi * 8;
  int bt, rbase; swz(blockIdx.x, bt, rbase);
  const int b = bt >> 1, tt = bt & 1;

  const unsigned* eh[2] = {ehZ, ehR};
  const unsigned* el[2] = {elZ, elR};

  // ---- A fragments straight from global (layout is fragment-compatible) ----
  short8 a_hi[2], a_lo[2];
  {
    const size_t row = (size_t)bt * NN + rbase + w * 16 + lane_lo;
#pragma unroll
    for (int g = 0; g < 2; ++g) {
      a_hi[g] = *(const short8*)((const short*)eh[g] + row * 32 + k0);
      a_lo[g] = *(const short8*)((const short*)el[g] + row * 32 + k0);
    }
  }

  // ---- prefetch registers (em tiles + xin) ----
  unsigned pem[2][2][4];
  unsigned pxw[4], psw[8];
  auto preload = [&](int mbase) {
#pragma unroll
    for (int g = 0; g < 2; ++g) {
      const unsigned* sh = eh[g] + ((size_t)bt * NN + mbase) * 16;
      const unsigned* sl = el[g] + ((size_t)bt * NN + mbase) * 16;
#pragma unroll
      for (int q = 0; q < 4; ++q) {
        int e = t + 256 * q;
        pem[g][0][q] = sh[e];
        pem[g][1][q] = sl[e];
      }
    }
#pragma unroll
    for (int q = 0; q < 4; ++q) {
      int e = t + 256 * q;
      int m = (e >> 5) * 2, c = e & 31;
      const float* xp = &x[((size_t)bt * NN + mbase + m) * DII + c];
      pxw[q] = pack2(xp[0], xp[DII]);
    }
#pragma unroll
    for (int q = 0; q < 8; ++q) {
      int e = t + 256 * q;
      int m = (e >> 6) * 2, d = e & 63;
      size_t sidx = (((size_t)b * THH + (THH - KTT) + tt) * NN + mbase + m) * DHD + d;
      psw[q] = pack2(states[sidx], states[sidx + DHD]);
    }
  };
  preload(0);

  float m_run[2][4], l_run[2][4];
#pragma unroll
  for (int g = 0; g < 2; ++g)
#pragma unroll
    for (int i = 0; i < 4; ++i) { m_run[g][i] = -1e30f; l_run[g][i] = 0.f; }
  f32x4 acc[2][6];
#pragma unroll
  for (int g = 0; g < 2; ++g)
#pragma unroll
    for (int j = 0; j < 6; ++j) acc[g][j] = (f32x4){0.f, 0.f, 0.f, 0.f};

  for (int mt = 0; mt < NN / MT; ++mt) {
    __syncthreads();
    // ---- write prefetched regs -> LDS ----
#pragma unroll
    for (int g = 0; g < 2; ++g)
#pragma unroll
      for (int q = 0; q < 4; ++q) {
        int e = t + 256 * q;
        int node = e >> 4, off = e & 15;
        ((unsigned*)s_em[g][0])[node * 20 + off] = pem[g][0][q];
        ((unsigned*)s_em[g][1])[node * 20 + off] = pem[g][1][q];
      }
#pragma unroll
    for (int q = 0; q < 4; ++q) {
      int e = t + 256 * q;
      int m2 = e >> 5, c = e & 31;
      int kc = m2 >> 4, g2 = (m2 >> 2) & 3, wd = m2 & 3;
      int nt = c >> 4, ll = c & 15;
      ((unsigned*)s_xt)[((kc * 6 + nt) * 64 + (ll + g2 * 16)) * 4 + wd] = pxw[q];
    }
#pragma unroll
    for (int q = 0; q < 8; ++q) {
      int e = t + 256 * q;
      int m2 = e >> 6, d = e & 63;
      int c = DII + d;
      int kc = m2 >> 4, g2 = (m2 >> 2) & 3, wd = m2 & 3;
      int nt = c >> 4, ll = c & 15;
      ((unsigned*)s_xt)[((kc * 6 + nt) * 64 + (ll + g2 * 16)) * 4 + wd] = psw[q];
    }
    __syncthreads();
    if (mt + 1 < NN / MT) preload((mt + 1) * MT);   // overlap with compute

    // ---- scores for both gates ----
    f32x4 sc[2][4];
#pragma unroll
    for (int g = 0; g < 2; ++g)
#pragma unroll
      for (int nt = 0; nt < 4; ++nt) {
        const short8 b_hi = *(const short8*)&s_em[g][0][(nt * 16 + lane_lo) * 40 + k0];
        const short8 b_lo = *(const short8*)&s_em[g][1][(nt * 16 + lane_lo) * 40 + k0];
        f32x4 c0 = (f32x4){0.f, 0.f, 0.f, 0.f};
        c0 = MFMA16(a_hi[g], b_hi, c0);
        c0 = MFMA16(a_hi[g], b_lo, c0);
        c0 = MFMA16(a_lo[g], b_hi, c0);
        sc[g][nt] = c0;
      }
    // ---- online softmax (per gate) ----
#pragma unroll
    for (int g = 0; g < 2; ++g) {
      float alpha[4], nm[4];
#pragma unroll
      for (int i = 0; i < 4; ++i) {
        float mx = fmaxf(fmaxf(sc[g][0][i], sc[g][1][i]),
                         fmaxf(sc[g][2][i], sc[g][3][i]));
        mx = fmaxf(mx, __shfl_xor(mx, 1, 64));
        mx = fmaxf(mx, __shfl_xor(mx, 2, 64));
        mx = fmaxf(mx, __shfl_xor(mx, 4, 64));
        mx = fmaxf(mx, __shfl_xor(mx, 8, 64));
        nm[i] = fmaxf(m_run[g][i], mx);
        alpha[i] = __expf(m_run[g][i] - nm[i]);
        m_run[g][i] = nm[i];
      }
      float rs[4] = {0.f, 0.f, 0.f, 0.f};
#pragma unroll
      for (int nt = 0; nt < 4; ++nt)
#pragma unroll
        for (int i = 0; i < 4; ++i) {
          float pv = __expf(sc[g][nt][i] - nm[i]);
          s_p[g][(w * 16 + lane_hi * 4 + i) * 72 + nt * 16 + lane_lo] = f2bf(pv);
          rs[i] += pv;
        }
#pragma unroll
      for (int i = 0; i < 4; ++i) {
        float s = rs[i];
        s += __shfl_xor(s, 1, 64);
        s += __shfl_xor(s, 2, 64);
        s += __shfl_xor(s, 4, 64);
        s += __shfl_xor(s, 8, 64);
        l_run[g][i] = l_run[g][i] * alpha[i] + s;
      }
#pragma unroll
      for (int j = 0; j < 6; ++j)
#pragma unroll
        for (int i = 0; i < 4; ++i) acc[g][j][i] *= alpha[i];
    }
    // ---- PV for both gates, sharing xin fragments ----
    const short8 paZ0 = *(const short8*)&s_p[0][(w * 16 + lane_lo) * 72 + k0];
    const short8 paZ1 = *(const short8*)&s_p[0][(w * 16 + lane_lo) * 72 + 32 + k0];
    const short8 paR0 = *(const short8*)&s_p[1][(w * 16 + lane_lo) * 72 + k0];
    const short8 paR1 = *(const short8*)&s_p[1][(w * 16 + lane_lo) * 72 + 32 + k0];
#pragma unroll
    for (int nt2 = 0; nt2 < 6; ++nt2) {
      const short8 xb0 = *(const short8*)&s_xt[((0 * 6 + nt2) * 64 + l) * 8];
      const short8 xb1 = *(const short8*)&s_xt[((1 * 6 + nt2) * 64 + l) * 8];
      acc[0][nt2] = MFMA16(paZ0, xb0, acc[0][nt2]);
      acc[0][nt2] = MFMA16(paZ1, xb1, acc[0][nt2]);
      acc[1][nt2] = MFMA16(paR0, xb0, acc[1][nt2]);
      acc[1][nt2] = MFMA16(paR1, xb1, acc[1][nt2]);
    }
  }
  // ---- epilogue ----
#pragma unroll
  for (int g = 0; g < 2; ++g) {
    unsigned short* Ax = g ? AxR : AxZ;
    float invl[4];
#pragma unroll
    for (int i = 0; i < 4; ++i) invl[i] = 1.f / l_run[g][i];
#pragma unroll
    for (int nt2 = 0; nt2 < 6; ++nt2)
#pragma unroll
      for (int i = 0; i < 4; ++i) {
        size_t o = ((size_t)bt * NN + rbase + w * 16 + lane_hi * 4 + i) * CC +
                   nt2 * 16 + lane_lo;
        Ax[o] = f2bf(acc[g][nt2][i] * invl[i]);
      }
  }
}

// ---------------- single-gate flash (u): xin = concat(x, z*state) ------------
__global__ __launch_bounds__(256, 2) void k_flash_u(
    const unsigned* __restrict__ emb_hi, const unsigned* __restrict__ emb_lo,
    const float* __restrict__ x, const float* __restrict__ states,
    const float* __restrict__ zbuf, unsigned short* __restrict__ Ax) {
  __shared__ unsigned short s_em_hi[MT * 40];
  __shared__ unsigned short s_em_lo[MT * 40];
  __shared__ unsigned short s_xt[2 * 6 * 64 * 8];
  __shared__ unsigned short s_p[RT * 72];

  const int t = threadIdx.x;
  const int w = t >> 6, l = t & 63;
  const int lane_lo = l & 15, lane_hi = l >> 4;
  const int k0 = lane_hi * 8;
  int bt, rbase; swz(blockIdx.x, bt, rbase);
  const int b = bt >> 1, tt = bt & 1;

  short8 a_hi, a_lo;
  {
    const size_t row = (size_t)bt * NN + rbase + w * 16 + lane_lo;
    a_hi = *(const short8*)((const short*)emb_hi + row * 32 + k0);
    a_lo = *(const short8*)((const short*)emb_lo + row * 32 + k0);
  }

  unsigned pemh[4], peml[4], pxw[4], psw[8];
  auto preload = [&](int mbase) {
    const unsigned* sh = emb_hi + ((size_t)bt * NN + mbase) * 16;
    const unsigned* sl = emb_lo + ((size_t)bt * NN + mbase) * 16;
#pragma unroll
    for (int q = 0; q < 4; ++q) {
      int e = t + 256 * q;
      pemh[q] = sh[e];
      peml[q] = sl[e];
    }
#pragma unroll
    for (int q = 0; q < 4; ++q) {
      int e = t + 256 * q;
      int m = (e >> 5) * 2, c = e & 31;
      const float* xp = &x[((size_t)bt * NN + mbase + m) * DII + c];
      pxw[q] = pack2(xp[0], xp[DII]);
    }
#pragma unroll
    for (int q = 0; q < 8; ++q) {
      int e = t + 256 * q;
      int m = (e >> 6) * 2, d = e & 63;
      size_t sidx = (((size_t)b * THH + (THH - KTT) + tt) * NN + mbase + m) * DHD + d;
      size_t zidx = ((size_t)bt * NN + mbase + m) * DHD + d;
      psw[q] = pack2(states[sidx] * zbuf[zidx], states[sidx + DHD] * zbuf[zidx + DHD]);
    }
  };
  preload(0);

  float m_run[4], l_run[4];
#pragma unroll
  for (int i = 0; i < 4; ++i) { m_run[i] = -1e30f; l_run[i] = 0.f; }
  f32x4 acc[6];
#pragma unroll
  for (int j = 0; j < 6; ++j) acc[j] = (f32x4){0.f, 0.f, 0.f, 0.f};

  for (int mt = 0; mt < NN / MT; ++mt) {
    __syncthreads();
#pragma unroll
    for (int q = 0; q < 4; ++q) {
      int e = t + 256 * q;
      int node = e >> 4, off = e & 15;
      ((unsigned*)s_em_hi)[node * 20 + off] = pemh[q];
      ((unsigned*)s_em_lo)[node * 20 + off] = peml[q];
    }
#pragma unroll
    for (int q = 0; q < 4; ++q) {
      int e = t + 256 * q;
      int m2 = e >> 5, c = e & 31;
      int kc = m2 >> 4, g2 = (m2 >> 2) & 3, wd = m2 & 3;
      int nt = c >> 4, ll = c & 15;
      ((unsigned*)s_xt)[((kc * 6 + nt) * 64 + (ll + g2 * 16)) * 4 + wd] = pxw[q];
    }
#pragma unroll
    for (int q = 0; q < 8; ++q) {
      int e = t + 256 * q;
      int m2 = e >> 6, d = e & 63;
      int c = DII + d;
      int kc = m2 >> 4, g2 = (m2 >> 2) & 3, wd = m2 & 3;
      int nt = c >> 4, ll = c & 15;
      ((unsigned*)s_xt)[((kc * 6 + nt) * 64 + (ll + g2 * 16)) * 4 + wd] = psw[q];
    }
    __syncthreads();
    if (mt + 1 < NN / MT) preload((mt + 1) * MT);

    f32x4 sc[4];
#pragma unroll
    for (int nt = 0; nt < 4; ++nt) {
      const short8 b_hi = *(const short8*)&s_em_hi[(nt * 16 + lane_lo) * 40 + k0];
      const short8 b_lo = *(const short8*)&s_em_lo[(nt * 16 + lane_lo) * 40 + k0];
      f32x4 c0 = (f32x4){0.f, 0.f, 0.f, 0.f};
      c0 = MFMA16(a_hi, b_hi, c0);
      c0 = MFMA16(a_hi, b_lo, c0);
      c0 = MFMA16(a_lo, b_hi, c0);
      sc[nt] = c0;
    }
    float alpha[4], nm[4];
#pragma unroll
    for (int i = 0; i < 4; ++i) {
      float mx = fmaxf(fmaxf(sc[0][i], sc[1][i]), fmaxf(sc[2][i], sc[3][i]));
      mx = fmaxf(mx, __shfl_xor(mx, 1, 64));
      mx = fmaxf(mx, __shfl_xor(mx, 2, 64));
      mx = fmaxf(mx, __shfl_xor(mx, 4, 64));
      mx = fmaxf(mx, __shfl_xor(mx, 8, 64));
      nm[i] = fmaxf(m_run[i], mx);
      alpha[i] = __expf(m_run[i] - nm[i]);
      m_run[i] = nm[i];
    }
    float rs[4] = {0.f, 0.f, 0.f, 0.f};
#pragma unroll
    for (int nt = 0; nt < 4; ++nt)
#pragma unroll
      for (int i = 0; i < 4; ++i) {
        float pv = __expf(sc[nt][i] - nm[i]);
        s_p[(w * 16 + lane_hi * 4 + i) * 72 + nt * 16 + lane_lo] = f2bf(pv);
        rs[i] += pv;
      }
#pragma unroll
    for (int i = 0; i < 4; ++i) {
      float s = rs[i];
      s += __shfl_xor(s, 1, 64);
      s += __shfl_xor(s, 2, 64);
      s += __shfl_xor(s, 4, 64);
      s += __shfl_xor(s, 8, 64);
      l_run[i] = l_run[i] * alpha[i] + s;
    }
#pragma unroll
    for (int j = 0; j < 6; ++j)
#pragma unroll
      for (int i = 0; i < 4; ++i) acc[j][i] *= alpha[i];
    const short8 pa0 = *(const short8*)&s_p[(w * 16 + lane_lo) * 72 + k0];
    const short8 pa1 = *(const short8*)&s_p[(w * 16 + lane_lo) * 72 + 32 + k0];
#pragma unroll
    for (int nt2 = 0; nt2 < 6; ++nt2) {
      const short8 xb0 = *(const short8*)&s_xt[((0 * 6 + nt2) * 64 + l) * 8];
      const short8 xb1 = *(const short8*)&s_xt[((1 * 6 + nt2) * 64 + l) * 8];
      acc[nt2] = MFMA16(pa0, xb0, acc[nt2]);
      acc[nt2] = MFMA16(pa1, xb1, acc[nt2]);
    }
  }
  float invl[4];
#pragma unroll
  for (int i = 0; i < 4; ++i) invl[i] = 1.f / l_run[i];
#pragma unroll
  for (int nt2 = 0; nt2 < 6; ++nt2)
#pragma unroll
    for (int i = 0; i < 4; ++i) {
      size_t o = ((size_t)bt * NN + rbase + w * 16 + lane_hi * 4 + i) * CC +
                 nt2 * 16 + lane_lo;
      Ax[o] = f2bf(acc[nt2][i] * invl[i]);
    }
}

// ------------- per-node weight matmul, NB=4 nodes/block, MFMA stage-2 --------
template <int MODE>
__global__ __launch_bounds__(256, 2) void k_nodemm(
    const float* __restrict__ x, const float* __restrict__ states,
    const float* __restrict__ zbuf, const unsigned short* __restrict__ Ax,
    const float* __restrict__ node_emb, const float* __restrict__ time_emb,
    const float* __restrict__ Wp, const float* __restrict__ bp,
    float* __restrict__ g) {
  __shared__ unsigned short s_W[4 * 6144];    // 49152 B
  __shared__ unsigned short s_xg[64 * 200];   // [(n*16+bt)][ki], 25600 B
  __shared__ float s_bias[BT * DHD];          // 4096 B

  const int t = threadIdx.x;
  const int w = t >> 6, l = t & 63;
  const int n0 = blockIdx.x * 4;

  float ne[4][DEE];
#pragma unroll
  for (int n = 0; n < 4; ++n)
#pragma unroll
    for (int d = 0; d < DEE; ++d) ne[n][d] = node_emb[(n0 + n) * DEE + d];

#pragma unroll
  for (int q = 0; q < 4; ++q) {
    int e = t + 256 * q;
    int bt = e >> 6, o = e & 63;
    float a = 0.f;
#pragma unroll
    for (int d = 0; d < DEE; ++d) a += time_emb[bt * DEE + d] * bp[d * DHD + o];
    s_bias[e] = a;
  }
#pragma unroll
  for (int q = 0; q < 48; ++q) {
    int e = t + 256 * q;
    int row = e / 192, ki = e - row * 192;
    int n = n0 + (row >> 4), bt = row & 15;
    unsigned short hv;
    if (ki < DII) {
      hv = f2bf(x[((size_t)bt * NN + n) * DII + ki]);
    } else if (ki < CC) {
      float v = states[(((size_t)(bt >> 1) * THH + (THH - KTT) + (bt & 1)) * NN + n) * DHD + (ki - DII)];
      if (MODE == 1) v *= zbuf[((size_t)bt * NN + n) * DHD + (ki - DII)];
      hv = f2bf(v);
    } else {
      hv = Ax[((size_t)bt * NN + n) * CC + (ki - CC)];
    }
    s_xg[row * 200 + ki] = hv;
  }
  __syncthreads();

  f32x4 acc[4];
#pragma unroll
  for (int ot = 0; ot < 4; ++ot) acc[ot] = (f32x4){0.f, 0.f, 0.f, 0.f};

  const int o0 = (t & 15) * 4;
  for (int pass = 0; pass < 2; ++pass) {
#pragma unroll
    for (int it = 0; it < 6; ++it) {
      const int j = pass * 6144 + it * 1024 + t * 4;
      const int ki = j >> 6;
      float f[4][4];
#pragma unroll
      for (int n = 0; n < 4; ++n)
#pragma unroll
        for (int c = 0; c < 4; ++c) f[n][c] = 0.f;
#pragma unroll
      for (int d = 0; d < DEE; ++d) {
        const float4 wq = *(const float4*)&Wp[(size_t)d * 12288 + j];
#pragma unroll
        for (int n = 0; n < 4; ++n) {
          f[n][0] = fmaf(ne[n][d], wq.x, f[n][0]);
          f[n][1] = fmaf(ne[n][d], wq.y, f[n][1]);
          f[n][2] = fmaf(ne[n][d], wq.z, f[n][2]);
          f[n][3] = fmaf(ne[n][d], wq.w, f[n][3]);
        }
      }
      const int kc = (ki >> 5) - pass * 3;
      const int kg = (ki >> 3) & 3, jj = ki & 7;
#pragma unroll
      for (int c = 0; c < 4; ++c) {
        const int oc = o0 + c;
        const int addr = ((kc * 4 + (oc >> 4)) * 64 + ((oc & 15) + kg * 16)) * 8 + jj;
#pragma unroll
        for (int n = 0; n < 4; ++n) s_W[n * 6144 + addr] = f2bf(f[n][c]);
      }
    }
    __syncthreads();
#pragma unroll
    for (int kc = 0; kc < 3; ++kc) {
      const short8 A = *(const short8*)
          &s_xg[(w * 16 + (l & 15)) * 200 + pass * 96 + kc * 32 + (l >> 4) * 8];
#pragma unroll
      for (int ot = 0; ot < 4; ++ot) {
        const short8 Bv = *(const short8*)&s_W[w * 6144 + ((kc * 4 + ot) * 64 + l) * 8];
        acc[ot] = MFMA16(A, Bv, acc[ot]);
      }
    }
    __syncthreads();
  }
  const int n = n0 + w;
#pragma unroll
  for (int ot = 0; ot < 4; ++ot)
#pragma unroll
    for (int i = 0; i < 4; ++i) {
      const int bt = (l >> 4) * 4 + i;
      const int o = ot * 16 + (l & 15);
      g[((size_t)bt * NN + n) * DHD + o] = acc[ot][i] + s_bias[bt * DHD + o];
    }
}

// --------------------- LN + tiny MHA + activation / gate ---------------------
__device__ __forceinline__ float wsum64(float v) {
#pragma unroll
  for (int off = 32; off > 0; off >>= 1) v += __shfl_xor(v, off, 64);
  return v;
}
__device__ __forceinline__ float hsum16(float v) {
  v += __shfl_xor(v, 8, 64);
  v += __shfl_xor(v, 4, 64);
  v += __shfl_xor(v, 2, 64);
  v += __shfl_xor(v, 1, 64);
  return v;
}

template <int MODE>
__global__ void k_attn(const float* __restrict__ g,
                       const float* __restrict__ states,
                       const float* __restrict__ lnOg,
                       const float* __restrict__ lnOb,
                       const float* __restrict__ rbuf,
                       float* __restrict__ dst) {
  const int lane = threadIdx.x & 63;
  const int unit = blockIdx.x * 4 + (threadIdx.x >> 6);  // b*NN + n
  const int b = unit >> 11;
  const int n = unit & (NN - 1);

  float kv[THH];
#pragma unroll
  for (int s = 0; s < THH; ++s)
    kv[s] = states[(((size_t)b * THH + s) * NN + n) * DHD + lane];
  const float go = lnOg[lane], bo = lnOb[lane];

#pragma unroll
  for (int tt = 0; tt < KTT; ++tt) {
    const size_t oi = (((size_t)b * KTT + tt) * NN + n) * DHD + lane;
    const float gval = g[oi];
    float mean = wsum64(gval) * (1.f / 64.f);
    float dv = gval - mean;
    float var = wsum64(dv * dv) * (1.f / 64.f);
    float q = dv * (1.f / sqrtf(var + 1e-5f)) * go + bo;
    float sc[THH];
#pragma unroll
    for (int s = 0; s < THH; ++s) sc[s] = hsum16(q * kv[s]) * 0.25f;
    float mx = sc[0];
#pragma unroll
    for (int s = 1; s < THH; ++s) mx = fmaxf(mx, sc[s]);
    float sum = 0.f;
#pragma unroll
    for (int s = 0; s < THH; ++s) { sc[s] = __expf(sc[s] - mx); sum += sc[s]; }
    float o = 0.f;
#pragma unroll
    for (int s = 0; s < THH; ++s) o += sc[s] * kv[s];
    o /= sum;
    const float val = gval + o;
    if (MODE == 0) {
      dst[oi] = 1.f / (1.f + __expf(-val));
    } else {
      const float hc = tanhf(val);
      const float stl =
          states[(((size_t)b * THH + (THH - KTT) + tt) * NN + n) * DHD + lane];
      const float rr = rbuf[oi];
      dst[oi] = rr * stl + (1.f - rr) * hc;
    }
  }
}

extern "C" void kernel_launch(void* const* d_in, const int* in_sizes, int n_in,
                              void* d_out, int out_size, void* d_ws, size_t ws_size,
                              hipStream_t stream) {
  const float* x        = (const float*)d_in[0];
  const float* states   = (const float*)d_in[1];
  const float* node_emb = (const float*)d_in[2];
  const float* time_emb = (const float*)d_in[3];

  unsigned char* wsb = (unsigned char*)d_ws;
  unsigned*       ehZ = (unsigned*)(wsb);              // 2MB each
  unsigned*       elZ = (unsigned*)(wsb + (2u << 20));
  unsigned*       ehR = (unsigned*)(wsb + (4u << 20));
  unsigned*       elR = (unsigned*)(wsb + (6u << 20));
  unsigned short* AxZ = (unsigned short*)(wsb + (8u << 20));   // 6MB
  unsigned short* AxR = (unsigned short*)(wsb + (14u << 20));  // 6MB
  float*          gb  = (float*)(wsb + (20u << 20));           // 8MB
  float*          zb  = (float*)(wsb + (28u << 20));           // 8MB
  float*          rb  = (float*)(wsb + (36u << 20));           // 8MB
  float* outp = (float*)d_out;

  struct Gate { const float *W, *bias, *lAg, *lAb, *lOg, *lOb; };
  auto G = [&](int i) {
    return Gate{(const float*)d_in[i],     (const float*)d_in[i + 1],
                (const float*)d_in[i + 2], (const float*)d_in[i + 3],
                (const float*)d_in[i + 4], (const float*)d_in[i + 5]};
  };
  Gate gz = G(4), gr = G(10), gu = G(16);

  const int gridE = BT * NN / 256;
  const int gridA = BB * NN / 4;
  const int gridF = (NN / RT) * BT;   // 512, swizzled inside
  const int gridN = NN / 4;           // 512

  // ---- z and r gates (shared xin) ----
  k_emb2<<<gridE, 256, 0, stream>>>(node_emb, time_emb, gz.lAg, gz.lAb,
                                    gr.lAg, gr.lAb, ehZ, elZ, ehR, elR);
  k_flash_zr<<<gridF, 256, 0, stream>>>(ehZ, elZ, ehR, elR, x, states, AxZ, AxR);
  k_nodemm<0><<<gridN, 256, 0, stream>>>(x, states, nullptr, AxZ, node_emb,
                                         time_emb, gz.W, gz.bias, gb);
  k_attn<0><<<gridA, 256, 0, stream>>>(gb, states, gz.lOg, gz.lOb, nullptr, zb);
  k_nodemm<0><<<gridN, 256, 0, stream>>>(x, states, nullptr, AxR, node_emb,
                                         time_emb, gr.W, gr.bias, gb);
  k_attn<0><<<gridA, 256, 0, stream>>>(gb, states, gr.lOg, gr.lOb, nullptr, rb);
  // ---- u gate + final combine ----
  k_emb<<<gridE, 256, 0, stream>>>(node_emb, time_emb, gu.lAg, gu.lAb, ehZ, elZ);
  k_flash_u<<<gridF, 256, 0, stream>>>(ehZ, elZ, x, states, zb, AxZ);
  k_nodemm<1><<<gridN, 256, 0, stream>>>(x, states, zb, AxZ, node_emb, time_emb,
                                         gu.W, gu.bias, gb);
  k_attn<1><<<gridA, 256, 0, stream>>>(gb, states, gu.lOg, gu.lOb, rb, outp);
}